// Round 3
// baseline (379.468 us; speedup 1.0000x reference)
//
#include <hip/hip_runtime.h>
#include <math.h>

// Problem constants (fixed by the reference)
#define SPATIAL (64*64*64)   // 262144 elements per (b, channel)
#define SPATIAL4 (SPATIAL/4) // 65536 float4 per channel
#define OCT4  (SPATIAL4/8)   // 8192 float4 per eighth-channel
#define NCH 64
#define BN_EPS 1e-5f

// clang-native 4-float vector for nontemporal builtins
typedef float v4f __attribute__((ext_vector_type(4)));

// -------- Kernel 1: partial sums, 8 blocks per (tensor,b,channel) ----------
// 2048 blocks x 256 threads -> 8 blocks/CU = 32 waves/CU (full occupancy,
// enforced by __launch_bounds__(256,8); kernel kept lean to fit 64 VGPR).
// 8 independent loads + 8 independent accumulators per batch -> deep vmcnt
// pipelining. g loads are NONTEMPORAL (g thrashes L3; keep x resident).
__global__ __launch_bounds__(256, 8) void mean_kernel(const float* __restrict__ g,
                                                      const float* __restrict__ x,
                                                      float* __restrict__ partial) {
    int blk = blockIdx.x;          // 0..2047
    int ch  = blk >> 3;            // 0..255 (0..127 = g channels, 128..255 = x)
    int oct = blk & 7;
    bool isg = ch < 128;
    const float* src = isg
        ? g + (size_t)ch * SPATIAL
        : x + (size_t)(ch - 128) * SPATIAL;
    const v4f* s4 = (const v4f*)src + (size_t)oct * OCT4 + threadIdx.x;

    float acc[8] = {0.f,0.f,0.f,0.f,0.f,0.f,0.f,0.f};
    if (isg) {
        for (int it = 0; it < 4; ++it) {          // 4 batches of 8 loads
            #pragma unroll
            for (int j = 0; j < 8; ++j) {
                v4f v = __builtin_nontemporal_load(s4 + j * 256);
                acc[j] += (v.x + v.y) + (v.z + v.w);
            }
            s4 += 2048;
        }
    } else {
        for (int it = 0; it < 4; ++it) {
            #pragma unroll
            for (int j = 0; j < 8; ++j) {
                v4f v = s4[j * 256];
                acc[j] += (v.x + v.y) + (v.z + v.w);
            }
            s4 += 2048;
        }
    }
    float sum = ((acc[0] + acc[1]) + (acc[2] + acc[3]))
              + ((acc[4] + acc[5]) + (acc[6] + acc[7]));

    // wave reduce (wave = 64)
    #pragma unroll
    for (int off = 32; off > 0; off >>= 1)
        sum += __shfl_down(sum, off, 64);
    __shared__ float wsum[4];
    int lane = threadIdx.x & 63, wave = threadIdx.x >> 6;
    if (lane == 0) wsum[wave] = sum;
    __syncthreads();
    if (threadIdx.x == 0)
        partial[blk] = wsum[0] + wsum[1] + wsum[2] + wsum[3];
}

// -------- Kernel 2: fold partials -> pooled, gating MLP -> 128 coefs -------
// 128 blocks (one per (b,gc)) x 64 threads (one per l). Coalesced w2 reads.
__global__ __launch_bounds__(64) void mlp_kernel(const float* __restrict__ partial,
                           const float* __restrict__ w1, const float* __restrict__ b1,
                           const float* __restrict__ w2, const float* __restrict__ b2,
                           const float* __restrict__ psi_w, const float* __restrict__ psi_b,
                           const float* __restrict__ bn_gamma, const float* __restrict__ bn_beta,
                           const float* __restrict__ bn_mean, const float* __restrict__ bn_var,
                           float* __restrict__ coef) {
    __shared__ float p[256];   // pooled, layout [b*128 + feature]
    __shared__ float h[32];    // hidden for this block's batch
    int tid = threadIdx.x;     // 0..63
    int blk = blockIdx.x;      // 0..127
    int b = blk >> 6, gc = blk & 63;

    // pooled: sum 8 partials per channel
    #pragma unroll
    for (int ch = tid; ch < 256; ch += 64) {
        const float* pp = partial + 8 * ch;
        float s = ((pp[0] + pp[1]) + (pp[2] + pp[3]))
                + ((pp[4] + pp[5]) + (pp[6] + pp[7]));
        int pi = (ch < 128) ? ((ch >> 6) * 128 + (ch & 63))
                            : (((ch - 128) >> 6) * 128 + 64 + ((ch - 128) & 63));
        p[pi] = s * (1.0f / SPATIAL);
    }
    __syncthreads();
    // hidden layer (redundant per block, cheap): threads 0..31
    if (tid < 32) {
        float acc = b1[tid];
        const float* wr = w1 + tid * 128;
        #pragma unroll 4
        for (int k = 0; k < 128; ++k) acc += p[b * 128 + k] * wr[k];
        h[tid] = fmaxf(acc, 0.f);
    }
    __syncthreads();
    // each thread: one l. w2 row contiguous 128B per lane, block reads 8KB.
    const float4* wr = (const float4*)(w2 + (size_t)(gc * 64 + tid) * 32);
    float z = b2[gc * 64 + tid];
    #pragma unroll
    for (int j = 0; j < 8; ++j) {
        float4 wv = wr[j];
        z += h[4*j] * wv.x + h[4*j+1] * wv.y + h[4*j+2] * wv.z + h[4*j+3] * wv.w;
    }
    float sig = 1.f / (1.f + expf(-z));   // dw[b,gc,l]
    float val = sig * psi_w[tid];
    #pragma unroll
    for (int off = 32; off > 0; off >>= 1)
        val += __shfl_down(val, off, 64);
    float scale = bn_gamma[0] * rsqrtf(bn_var[0] + BN_EPS);
    if (tid == 0) coef[b * 64 + gc] = val * scale;
    if (blk == 0 && tid == 0)
        coef[128] = (psi_b[0] - bn_mean[0]) * scale + bn_beta[0];
}

// -------- Kernel 3: s = sum_g g*c ; out = x * sigmoid(s + bias) ------------
// 2048 blocks x 256 threads (8 blocks/CU = 32 waves/CU). Each block owns 64
// float4 positions; 4 thread-groups of 64 each reduce 16 g-channels, combine
// via LDS, then each group writes 16 x-channels.
// g loads NONTEMPORAL (last use, don't pollute L3); x loads normal (should
// hit L3, kept resident by the g-nt policy); out stores NONTEMPORAL.
__device__ __forceinline__ void fma4(v4f& a, v4f v, float c) {
    a.x += v.x * c; a.y += v.y * c; a.z += v.z * c; a.w += v.w * c;
}

__global__ __launch_bounds__(256, 8) void apply_kernel(const float* __restrict__ g,
                                                       const float* __restrict__ x,
                                                       const float* __restrict__ coef,
                                                       float* __restrict__ out) {
    int t    = threadIdx.x;
    int pos  = t & 63;
    int grp  = t >> 6;                        // 0..3
    int blk  = blockIdx.x;                    // 0..2047
    int batch = blk >> 10;                    // 1024 blocks per batch
    int base4 = (blk & 1023) * 64 + pos;      // float4 index within channel
    size_t bOff = (size_t)batch * NCH * SPATIAL4;

    const v4f* g4 = (const v4f*)g;
    const v4f* x4 = (const v4f*)x;
    v4f* o4 = (v4f*)out;

    const v4f* cfv = (const v4f*)(coef + batch * NCH + grp * 16);
    const v4f* gp = g4 + bOff + (size_t)(grp * 16) * SPATIAL4 + base4;

    v4f acc0 = {0.f,0.f,0.f,0.f}, acc1 = {0.f,0.f,0.f,0.f};
    #pragma unroll
    for (int bq = 0; bq < 4; ++bq) {          // 4 batches of 4 indep loads
        v4f cv = cfv[bq];
        v4f v0 = __builtin_nontemporal_load(gp + (size_t)(4*bq + 0) * SPATIAL4);
        v4f v1 = __builtin_nontemporal_load(gp + (size_t)(4*bq + 1) * SPATIAL4);
        v4f v2 = __builtin_nontemporal_load(gp + (size_t)(4*bq + 2) * SPATIAL4);
        v4f v3 = __builtin_nontemporal_load(gp + (size_t)(4*bq + 3) * SPATIAL4);
        fma4(acc0, v0, cv.x);
        fma4(acc1, v1, cv.y);
        fma4(acc0, v2, cv.z);
        fma4(acc1, v3, cv.w);
    }
    v4f acc = {acc0.x + acc1.x, acc0.y + acc1.y, acc0.z + acc1.z, acc0.w + acc1.w};

    __shared__ v4f red[4][64];
    if (grp != 0) red[grp][pos] = acc;
    __syncthreads();
    if (grp == 0) {
        v4f r1 = red[1][pos], r2 = red[2][pos], r3 = red[3][pos];
        float d = coef[128];
        v4f s;
        s.x = 1.f / (1.f + expf(-(acc.x + r1.x + r2.x + r3.x + d)));
        s.y = 1.f / (1.f + expf(-(acc.y + r1.y + r2.y + r3.y + d)));
        s.z = 1.f / (1.f + expf(-(acc.z + r1.z + r2.z + r3.z + d)));
        s.w = 1.f / (1.f + expf(-(acc.w + r1.w + r2.w + r3.w + d)));
        red[0][pos] = s;
    }
    __syncthreads();
    v4f s = red[0][pos];

    const v4f* xp = x4 + bOff + (size_t)(grp * 16) * SPATIAL4 + base4;
    v4f*       op = o4 + bOff + (size_t)(grp * 16) * SPATIAL4 + base4;
    #pragma unroll 4
    for (int l = 0; l < 16; ++l) {
        v4f xv = xp[(size_t)l * SPATIAL4];
        v4f ov = {xv.x * s.x, xv.y * s.y, xv.z * s.z, xv.w * s.w};
        __builtin_nontemporal_store(ov, op + (size_t)l * SPATIAL4);
    }
}

extern "C" void kernel_launch(void* const* d_in, const int* in_sizes, int n_in,
                              void* d_out, int out_size, void* d_ws, size_t ws_size,
                              hipStream_t stream) {
    const float* g        = (const float*)d_in[0];
    const float* x        = (const float*)d_in[1];
    const float* w1       = (const float*)d_in[2];
    const float* b1       = (const float*)d_in[3];
    const float* w2       = (const float*)d_in[4];
    const float* b2       = (const float*)d_in[5];
    const float* psi_w    = (const float*)d_in[6];
    const float* psi_b    = (const float*)d_in[7];
    const float* bn_gamma = (const float*)d_in[8];
    const float* bn_beta  = (const float*)d_in[9];
    const float* bn_mean  = (const float*)d_in[10];
    const float* bn_var   = (const float*)d_in[11];
    float* out = (float*)d_out;
    float* ws  = (float*)d_ws;

    float* partial = ws;         // 2048 floats
    float* coef    = ws + 2048;  // 129 floats

    mean_kernel<<<2048, 256, 0, stream>>>(g, x, partial);
    mlp_kernel<<<128, 64, 0, stream>>>(partial, w1, b1, w2, b2, psi_w, psi_b,
                                       bn_gamma, bn_beta, bn_mean, bn_var, coef);
    apply_kernel<<<2048, 256, 0, stream>>>(g, x, coef, out);
}

// Round 4
// 378.145 us; speedup vs baseline: 1.0035x; 1.0035x over previous
//
#include <hip/hip_runtime.h>
#include <math.h>

// Problem constants (fixed by the reference)
#define SPATIAL (64*64*64)   // 262144 elements per (b, channel)
#define SPATIAL4 (SPATIAL/4) // 65536 float4 per channel
#define NCH 64
#define BN_EPS 1e-5f

#define NBLK   2048          // mean grid
#define NTILE  65536         // 4 KB tiles covering g then x (268 MB total)
#define GTILES 32768         // tiles belonging to g

// clang-native 4-float vector for nontemporal builtins
typedef float v4f __attribute__((ext_vector_type(4)));

// -------- Kernel 1: dense-front partial sums -------------------------------
// Grid-stride over 4 KB tiles: at iteration k ALL 2048 blocks read one
// contiguous 8 MB window (tile T = k*2048 + b) -> a single dense sweeping
// front, the DRAM-friendliest pattern (what the 6.3 TB/s copy ubench does),
// instead of 2048 scattered private streams (stuck at 2.7 TB/s in r2/r3).
// Each 1 KB wave-segment lies in exactly one channel (64 | 65536), so a
// 6-step wave reduce gives one partial; every wave writes a UNIQUE slot
// (no atomics, no zeroing, deterministic).
__global__ __launch_bounds__(256) void mean_kernel(const float* __restrict__ g,
                                                   const float* __restrict__ x,
                                                   float* __restrict__ wpart) {
    int b    = blockIdx.x;        // 0..2047
    int tid  = threadIdx.x;       // 0..255
    int lane = tid & 63, wave = tid >> 6;
    const v4f* g4 = (const v4f*)g;
    const v4f* x4 = (const v4f*)x;

    #pragma unroll 4
    for (int k = 0; k < 32; ++k) {
        int T = k * NBLK + b;     // tile index, 0..65535
        const v4f* src = (T < GTILES) ? (g4 + (size_t)T * 256)
                                      : (x4 + (size_t)(T - GTILES) * 256);
        v4f v = src[tid];
        float s = (v.x + v.y) + (v.z + v.w);
        #pragma unroll
        for (int off = 32; off > 0; off >>= 1)
            s += __shfl_down(s, off, 64);
        if (lane == 0) wpart[T * 4 + wave] = s;   // unique slot per wave
    }
}

// -------- Kernel 1b: fold 1024 wave-partials per channel -> pooled ---------
// Channel ch owns tiles [ch*256, ch*256+256) -> wpart[ch*1024 .. +1024),
// contiguous. 256 blocks x 256 threads, ~1 MB read. Writes pooled[] already
// in the MLP's remapped layout [b*128 + feature].
__global__ __launch_bounds__(256) void fold_kernel(const float* __restrict__ wpart,
                                                   float* __restrict__ pooled) {
    int ch  = blockIdx.x;         // 0..255
    int tid = threadIdx.x;
    const v4f* src = (const v4f*)(wpart + (size_t)ch * 1024);
    v4f v = src[tid];
    float s = (v.x + v.y) + (v.z + v.w);
    #pragma unroll
    for (int off = 32; off > 0; off >>= 1)
        s += __shfl_down(s, off, 64);
    __shared__ float ws[4];
    if ((tid & 63) == 0) ws[tid >> 6] = s;
    __syncthreads();
    if (tid == 0) {
        float tot = (ws[0] + ws[1]) + (ws[2] + ws[3]);
        int pi = (ch < 128) ? ((ch >> 6) * 128 + (ch & 63))
                            : (((ch - 128) >> 6) * 128 + 64 + ((ch - 128) & 63));
        pooled[pi] = tot * (1.0f / SPATIAL);
    }
}

// -------- Kernel 2: gating MLP -> 128 coefs + bias -------------------------
// 128 blocks (one per (b,gc)) x 64 threads (one per l). Coalesced w2 reads.
__global__ __launch_bounds__(64) void mlp_kernel(const float* __restrict__ pooled,
                           const float* __restrict__ w1, const float* __restrict__ b1,
                           const float* __restrict__ w2, const float* __restrict__ b2,
                           const float* __restrict__ psi_w, const float* __restrict__ psi_b,
                           const float* __restrict__ bn_gamma, const float* __restrict__ bn_beta,
                           const float* __restrict__ bn_mean, const float* __restrict__ bn_var,
                           float* __restrict__ coef) {
    __shared__ float p[256];   // pooled, layout [b*128 + feature]
    __shared__ float h[32];    // hidden for this block's batch
    int tid = threadIdx.x;     // 0..63
    int blk = blockIdx.x;      // 0..127
    int b = blk >> 6, gc = blk & 63;

    #pragma unroll
    for (int i = tid; i < 256; i += 64) p[i] = pooled[i];
    __syncthreads();
    // hidden layer (redundant per block, cheap): threads 0..31
    if (tid < 32) {
        float acc = b1[tid];
        const float* wr = w1 + tid * 128;
        #pragma unroll 4
        for (int k = 0; k < 128; ++k) acc += p[b * 128 + k] * wr[k];
        h[tid] = fmaxf(acc, 0.f);
    }
    __syncthreads();
    // each thread: one l. w2 row contiguous 128B per lane, block reads 8KB.
    const float4* wr = (const float4*)(w2 + (size_t)(gc * 64 + tid) * 32);
    float z = b2[gc * 64 + tid];
    #pragma unroll
    for (int j = 0; j < 8; ++j) {
        float4 wv = wr[j];
        z += h[4*j] * wv.x + h[4*j+1] * wv.y + h[4*j+2] * wv.z + h[4*j+3] * wv.w;
    }
    float sig = 1.f / (1.f + expf(-z));   // dw[b,gc,l]
    float val = sig * psi_w[tid];
    #pragma unroll
    for (int off = 32; off > 0; off >>= 1)
        val += __shfl_down(val, off, 64);
    float scale = bn_gamma[0] * rsqrtf(bn_var[0] + BN_EPS);
    if (tid == 0) coef[b * 64 + gc] = val * scale;
    if (blk == 0 && tid == 0)
        coef[128] = (psi_b[0] - bn_mean[0]) * scale + bn_beta[0];
}

// -------- Kernel 3: s = sum_g g*c ; out = x * sigmoid(s + bias) ------------
// (unchanged from round 3 — verified; one variable per round)
__device__ __forceinline__ void fma4(v4f& a, v4f v, float c) {
    a.x += v.x * c; a.y += v.y * c; a.z += v.z * c; a.w += v.w * c;
}

__global__ __launch_bounds__(256, 8) void apply_kernel(const float* __restrict__ g,
                                                       const float* __restrict__ x,
                                                       const float* __restrict__ coef,
                                                       float* __restrict__ out) {
    int t    = threadIdx.x;
    int pos  = t & 63;
    int grp  = t >> 6;                        // 0..3
    int blk  = blockIdx.x;                    // 0..2047
    int batch = blk >> 10;                    // 1024 blocks per batch
    int base4 = (blk & 1023) * 64 + pos;      // float4 index within channel
    size_t bOff = (size_t)batch * NCH * SPATIAL4;

    const v4f* g4 = (const v4f*)g;
    const v4f* x4 = (const v4f*)x;
    v4f* o4 = (v4f*)out;

    const v4f* cfv = (const v4f*)(coef + batch * NCH + grp * 16);
    const v4f* gp = g4 + bOff + (size_t)(grp * 16) * SPATIAL4 + base4;

    v4f acc0 = {0.f,0.f,0.f,0.f}, acc1 = {0.f,0.f,0.f,0.f};
    #pragma unroll
    for (int bq = 0; bq < 4; ++bq) {          // 4 batches of 4 indep loads
        v4f cv = cfv[bq];
        v4f v0 = __builtin_nontemporal_load(gp + (size_t)(4*bq + 0) * SPATIAL4);
        v4f v1 = __builtin_nontemporal_load(gp + (size_t)(4*bq + 1) * SPATIAL4);
        v4f v2 = __builtin_nontemporal_load(gp + (size_t)(4*bq + 2) * SPATIAL4);
        v4f v3 = __builtin_nontemporal_load(gp + (size_t)(4*bq + 3) * SPATIAL4);
        fma4(acc0, v0, cv.x);
        fma4(acc1, v1, cv.y);
        fma4(acc0, v2, cv.z);
        fma4(acc1, v3, cv.w);
    }
    v4f acc = {acc0.x + acc1.x, acc0.y + acc1.y, acc0.z + acc1.z, acc0.w + acc1.w};

    __shared__ v4f red[4][64];
    if (grp != 0) red[grp][pos] = acc;
    __syncthreads();
    if (grp == 0) {
        v4f r1 = red[1][pos], r2 = red[2][pos], r3 = red[3][pos];
        float d = coef[128];
        v4f s;
        s.x = 1.f / (1.f + expf(-(acc.x + r1.x + r2.x + r3.x + d)));
        s.y = 1.f / (1.f + expf(-(acc.y + r1.y + r2.y + r3.y + d)));
        s.z = 1.f / (1.f + expf(-(acc.z + r1.z + r2.z + r3.z + d)));
        s.w = 1.f / (1.f + expf(-(acc.w + r1.w + r2.w + r3.w + d)));
        red[0][pos] = s;
    }
    __syncthreads();
    v4f s = red[0][pos];

    const v4f* xp = x4 + bOff + (size_t)(grp * 16) * SPATIAL4 + base4;
    v4f*       op = o4 + bOff + (size_t)(grp * 16) * SPATIAL4 + base4;
    #pragma unroll 4
    for (int l = 0; l < 16; ++l) {
        v4f xv = xp[(size_t)l * SPATIAL4];
        v4f ov = {xv.x * s.x, xv.y * s.y, xv.z * s.z, xv.w * s.w};
        __builtin_nontemporal_store(ov, op + (size_t)l * SPATIAL4);
    }
}

extern "C" void kernel_launch(void* const* d_in, const int* in_sizes, int n_in,
                              void* d_out, int out_size, void* d_ws, size_t ws_size,
                              hipStream_t stream) {
    const float* g        = (const float*)d_in[0];
    const float* x        = (const float*)d_in[1];
    const float* w1       = (const float*)d_in[2];
    const float* b1       = (const float*)d_in[3];
    const float* w2       = (const float*)d_in[4];
    const float* b2       = (const float*)d_in[5];
    const float* psi_w    = (const float*)d_in[6];
    const float* psi_b    = (const float*)d_in[7];
    const float* bn_gamma = (const float*)d_in[8];
    const float* bn_beta  = (const float*)d_in[9];
    const float* bn_mean  = (const float*)d_in[10];
    const float* bn_var   = (const float*)d_in[11];
    float* out = (float*)d_out;
    float* ws  = (float*)d_ws;

    float* wpart  = ws;                   // 262144 floats (1 MB)
    float* pooled = ws + NTILE * 4;       // 256 floats
    float* coef   = pooled + 256;         // 129 floats

    mean_kernel<<<NBLK, 256, 0, stream>>>(g, x, wpart);
    fold_kernel<<<256, 256, 0, stream>>>(wpart, pooled);
    mlp_kernel<<<128, 64, 0, stream>>>(pooled, w1, b1, w2, b2, psi_w, psi_b,
                                       bn_gamma, bn_beta, bn_mean, bn_var, coef);
    apply_kernel<<<2048, 256, 0, stream>>>(g, x, coef, out);
}